// Round 1
// baseline (1146.063 us; speedup 1.0000x reference)
//
#include <hip/hip_runtime.h>
#include <stdint.h>

#define HMAP   (1u << 19)
#define HMASK  (HMAP - 1u)
#define NPTS_BLK 128

typedef short bf16x8 __attribute__((ext_vector_type(8)));
typedef float f32x4  __attribute__((ext_vector_type(4)));

// resolutions: ceil(16 * 2^(7l/15)); dense (R^3 <= 2^19) for levels 0..4
__device__ __constant__ const int c_res[16] = {16, 23, 31, 43, 59, 81, 112, 154, 213, 295, 407, 562, 777, 1073, 1483, 2048};

__device__ __forceinline__ unsigned short f2bf(float f) {
    unsigned u = __float_as_uint(f);
    u += 0x7fffu + ((u >> 16) & 1u);           // round-to-nearest-even
    return (unsigned short)(u >> 16);
}

__device__ __forceinline__ float softplus100(float v) {
    return (v > 0.2f) ? v : 0.01f * log1pf(__expf(100.0f * v));
}

__device__ __forceinline__ float2 gather_level(const float* __restrict__ tab, int R,
                                               float x0, float x1, float x2) {
    const float Rm1 = (float)(R - 1);
    float px = x0 * Rm1, py = x1 * Rm1, pz = x2 * Rm1;
    float fx = floorf(px), fy = floorf(py), fz = floorf(pz);
    float wx = px - fx, wy = py - fy, wz = pz - fz;
    int ix = (int)fx, iy = (int)fy, iz = (int)fz;
    ix = max(0, min(ix, R - 1)); iy = max(0, min(iy, R - 1)); iz = max(0, min(iz, R - 1));
    int jx = min(ix + 1, R - 1), jy = min(iy + 1, R - 1), jz = min(iz + 1, R - 1);
    unsigned i0, i1, i2, i3, i4, i5, i6, i7;
    if ((long long)R * R * R <= (long long)HMAP) {   // dense — folds at compile time per level
        unsigned sy = (unsigned)R, sz = (unsigned)(R * R);
        unsigned X0 = (unsigned)ix, X1 = (unsigned)jx;
        unsigned Y0 = (unsigned)iy * sy, Y1 = (unsigned)jy * sy;
        unsigned Z0 = (unsigned)iz * sz, Z1 = (unsigned)jz * sz;
        i0 = X0 + Y0 + Z0; i1 = X0 + Y0 + Z1; i2 = X0 + Y1 + Z0; i3 = X0 + Y1 + Z1;
        i4 = X1 + Y0 + Z0; i5 = X1 + Y0 + Z1; i6 = X1 + Y1 + Z0; i7 = X1 + Y1 + Z1;
    } else {                                          // hashed
        unsigned X0 = (unsigned)ix, X1 = (unsigned)jx;
        unsigned Y0 = (unsigned)iy * 2654435761u, Y1 = (unsigned)jy * 2654435761u;
        unsigned Z0 = (unsigned)iz * 805459861u,  Z1 = (unsigned)jz * 805459861u;
        i0 = (X0 ^ Y0 ^ Z0) & HMASK; i1 = (X0 ^ Y0 ^ Z1) & HMASK;
        i2 = (X0 ^ Y1 ^ Z0) & HMASK; i3 = (X0 ^ Y1 ^ Z1) & HMASK;
        i4 = (X1 ^ Y0 ^ Z0) & HMASK; i5 = (X1 ^ Y0 ^ Z1) & HMASK;
        i6 = (X1 ^ Y1 ^ Z0) & HMASK; i7 = (X1 ^ Y1 ^ Z1) & HMASK;
    }
    const float2* t2 = (const float2*)tab;
    float2 v0 = t2[i0], v1 = t2[i1], v2 = t2[i2], v3 = t2[i3];
    float2 v4 = t2[i4], v5 = t2[i5], v6 = t2[i6], v7 = t2[i7];
    float ax = 1.f - wx, ay = 1.f - wy, az = 1.f - wz;
    float w00 = ay * az, w01 = ay * wz, w10 = wy * az, w11 = wy * wz;
    float c0 = ax * w00, c1 = ax * w01, c2 = ax * w10, c3 = ax * w11;
    float c4 = wx * w00, c5 = wx * w01, c6 = wx * w10, c7 = wx * w11;
    float2 r;
    r.x = c0 * v0.x + c1 * v1.x + c2 * v2.x + c3 * v3.x + c4 * v4.x + c5 * v5.x + c6 * v6.x + c7 * v7.x;
    r.y = c0 * v0.y + c1 * v1.y + c2 * v2.y + c3 * v3.y + c4 * v4.y + c5 * v5.y + c6 * v6.y + c7 * v7.y;
    return r;
}

// LDS layout (unsigned short units)
#define SA_STRIDE 104                     // 96 K-cols + pad (stride 208B -> 2-way banks, free)
#define SA_OFF    0                       // 128 * 104
#define SB0_OFF   (128 * 104)             // W0 bf16  [64][104]  (cols 71..95 zero)
#define SB1_OFF   (SB0_OFF + 64 * 104)    // W1 bf16  [64][72]
#define SB2_OFF   (SB1_OFF + 64 * 72)     // W2 bf16  [32][72]  (rows 17..31 zero)
#define SMEM_TOT  (SB2_OFF + 32 * 72)     // 26880 shorts = 53760 B -> 3 blocks/CU

__global__ __launch_bounds__(256, 3)
void gn_fused(const float* __restrict__ x, const float* __restrict__ tables,
              const float* __restrict__ W0, const float* __restrict__ b0,
              const float* __restrict__ W1, const float* __restrict__ b1,
              const float* __restrict__ W2, const float* __restrict__ b2,
              float* __restrict__ out) {
    __shared__ unsigned short smem[SMEM_TOT];
    const int tid = threadIdx.x;
    const int blk = blockIdx.x;

    // ---- stage weights as bf16 (zero-padded) ----
    for (int i = tid; i < 64 * 104; i += 256) {
        int n = i / 104, k = i - n * 104;
        smem[SB0_OFF + i] = f2bf((k < 71) ? W0[n * 71 + k] : 0.f);
    }
    for (int i = tid; i < 64 * 72; i += 256) {
        int n = i / 72, k = i - n * 72;
        smem[SB1_OFF + i] = f2bf((k < 64) ? W1[n * 64 + k] : 0.f);
    }
    for (int i = tid; i < 32 * 72; i += 256) {
        int n = i / 72, k = i - n * 72;
        smem[SB2_OFF + i] = f2bf((n < 17 && k < 64) ? W2[n * 64 + k] : 0.f);
    }

    // ---- feature phase: 2 threads per point (even/odd level split) ----
    {
        const int p  = tid & 127;
        const int gp = blk * NPTS_BLK + p;
        const float x0 = x[3 * gp], x1 = x[3 * gp + 1], x2 = x[3 * gp + 2];
        unsigned short* row = &smem[SA_OFF + p * SA_STRIDE];
        if (tid < 128) {
            row[0] = f2bf(x0); row[1] = f2bf(x1); row[2] = f2bf(x2);
            float fr = 1.f;
            #pragma unroll
            for (int m = 0; m < 6; ++m) {
                float a0 = x0 * fr, a1 = x1 * fr, a2 = x2 * fr;
                row[3 + 6 * m + 0] = f2bf(__sinf(a0));
                row[3 + 6 * m + 1] = f2bf(__sinf(a1));
                row[3 + 6 * m + 2] = f2bf(__sinf(a2));
                row[3 + 6 * m + 3] = f2bf(__cosf(a0));
                row[3 + 6 * m + 4] = f2bf(__cosf(a1));
                row[3 + 6 * m + 5] = f2bf(__cosf(a2));
                fr *= 2.f;
            }
            #pragma unroll
            for (int li = 0; li < 8; ++li) {        // even levels
                const int l = 2 * li;
                float2 f = gather_level(tables + (size_t)l * (2u * HMAP), c_res[l], x0, x1, x2);
                row[39 + 2 * l] = f2bf(f.x);
                row[40 + 2 * l] = f2bf(f.y);
            }
            #pragma unroll
            for (int k = 71; k < 96; ++k) row[k] = 0;   // zero K-pad
        } else {
            #pragma unroll
            for (int li = 0; li < 8; ++li) {        // odd levels
                const int l = 2 * li + 1;
                float2 f = gather_level(tables + (size_t)l * (2u * HMAP), c_res[l], x0, x1, x2);
                row[39 + 2 * l] = f2bf(f.x);
                row[40 + 2 * l] = f2bf(f.y);
            }
        }
    }
    __syncthreads();

    // ---- MFMA pipeline: wave w -> m-half (w&1)*64, n-half (w>>1)*32 ----
    const int wave  = tid >> 6;
    const int lane  = tid & 63;
    const int mhalf = (wave & 1) * 64;
    const int nhalf = (wave >> 1);
    const int lrow  = lane & 15;
    const int quad  = lane >> 4;

    // Layer 0: [128x96] x [96x64]
    f32x4 acc0[4][2];
    #pragma unroll
    for (int mt = 0; mt < 4; ++mt)
        #pragma unroll
        for (int nt = 0; nt < 2; ++nt) acc0[mt][nt] = (f32x4){0.f, 0.f, 0.f, 0.f};
    #pragma unroll
    for (int ks = 0; ks < 3; ++ks) {
        bf16x8 bfr[2];
        #pragma unroll
        for (int nt = 0; nt < 2; ++nt) {
            int n = nhalf * 32 + nt * 16 + lrow;
            bfr[nt] = *(const bf16x8*)&smem[SB0_OFF + n * 104 + ks * 32 + quad * 8];
        }
        #pragma unroll
        for (int mt = 0; mt < 4; ++mt) {
            int m = mhalf + mt * 16 + lrow;
            bf16x8 afr = *(const bf16x8*)&smem[SA_OFF + m * SA_STRIDE + ks * 32 + quad * 8];
            #pragma unroll
            for (int nt = 0; nt < 2; ++nt)
                acc0[mt][nt] = __builtin_amdgcn_mfma_f32_16x16x32_bf16(afr, bfr[nt], acc0[mt][nt], 0, 0, 0);
        }
    }
    __syncthreads();   // all A-reads done before overwriting sA with h0
    #pragma unroll
    for (int mt = 0; mt < 4; ++mt)
        #pragma unroll
        for (int nt = 0; nt < 2; ++nt) {
            int colg = nhalf * 32 + nt * 16 + lrow;
            float bias = b0[colg];
            #pragma unroll
            for (int r = 0; r < 4; ++r) {
                int rowm = mhalf + mt * 16 + quad * 4 + r;
                smem[SA_OFF + rowm * SA_STRIDE + colg] = f2bf(softplus100(acc0[mt][nt][r] + bias));
            }
        }
    __syncthreads();

    // Layer 1: [128x64] x [64x64]
    f32x4 acc1[4][2];
    #pragma unroll
    for (int mt = 0; mt < 4; ++mt)
        #pragma unroll
        for (int nt = 0; nt < 2; ++nt) acc1[mt][nt] = (f32x4){0.f, 0.f, 0.f, 0.f};
    #pragma unroll
    for (int ks = 0; ks < 2; ++ks) {
        bf16x8 bfr[2];
        #pragma unroll
        for (int nt = 0; nt < 2; ++nt) {
            int n = nhalf * 32 + nt * 16 + lrow;
            bfr[nt] = *(const bf16x8*)&smem[SB1_OFF + n * 72 + ks * 32 + quad * 8];
        }
        #pragma unroll
        for (int mt = 0; mt < 4; ++mt) {
            int m = mhalf + mt * 16 + lrow;
            bf16x8 afr = *(const bf16x8*)&smem[SA_OFF + m * SA_STRIDE + ks * 32 + quad * 8];
            #pragma unroll
            for (int nt = 0; nt < 2; ++nt)
                acc1[mt][nt] = __builtin_amdgcn_mfma_f32_16x16x32_bf16(afr, bfr[nt], acc1[mt][nt], 0, 0, 0);
        }
    }
    __syncthreads();
    #pragma unroll
    for (int mt = 0; mt < 4; ++mt)
        #pragma unroll
        for (int nt = 0; nt < 2; ++nt) {
            int colg = nhalf * 32 + nt * 16 + lrow;
            float bias = b1[colg];
            #pragma unroll
            for (int r = 0; r < 4; ++r) {
                int rowm = mhalf + mt * 16 + quad * 4 + r;
                smem[SA_OFF + rowm * SA_STRIDE + colg] = f2bf(softplus100(acc1[mt][nt][r] + bias));
            }
        }
    __syncthreads();

    // Layer 2: [128x64] x [64x32] (cols 17..31 are zero-padding)
    f32x4 acc2[4];
    #pragma unroll
    for (int mt = 0; mt < 4; ++mt) acc2[mt] = (f32x4){0.f, 0.f, 0.f, 0.f};
    #pragma unroll
    for (int ks = 0; ks < 2; ++ks) {
        int n = nhalf * 16 + lrow;
        bf16x8 bfr = *(const bf16x8*)&smem[SB2_OFF + n * 72 + ks * 32 + quad * 8];
        #pragma unroll
        for (int mt = 0; mt < 4; ++mt) {
            int m = mhalf + mt * 16 + lrow;
            bf16x8 afr = *(const bf16x8*)&smem[SA_OFF + m * SA_STRIDE + ks * 32 + quad * 8];
            acc2[mt] = __builtin_amdgcn_mfma_f32_16x16x32_bf16(afr, bfr, acc2[mt], 0, 0, 0);
        }
    }
    // epilogue -> sOut (aliases sB0 region; its last reads were in layer 0, barrier-separated)
    float* sOut = (float*)&smem[SB0_OFF];
    {
        int colg = nhalf * 16 + lrow;
        if (colg < 17) {
            float bias = b2[colg];
            #pragma unroll
            for (int mt = 0; mt < 4; ++mt)
                #pragma unroll
                for (int r = 0; r < 4; ++r) {
                    int rowm = mhalf + mt * 16 + quad * 4 + r;
                    sOut[rowm * 17 + colg] = acc2[mt][r] + bias;
                }
        }
    }
    __syncthreads();

    // coalesced store of [128 x 17] fp32
    const size_t obase = (size_t)blk * (NPTS_BLK * 17);
    for (int i = tid; i < NPTS_BLK * 17; i += 256) out[obase + i] = sOut[i];
}

extern "C" void kernel_launch(void* const* d_in, const int* in_sizes, int n_in,
                              void* d_out, int out_size, void* d_ws, size_t ws_size,
                              hipStream_t stream) {
    const float* x      = (const float*)d_in[0];
    const float* tables = (const float*)d_in[1];
    const float* W0     = (const float*)d_in[2];
    const float* b0     = (const float*)d_in[3];
    const float* W1     = (const float*)d_in[4];
    const float* b1     = (const float*)d_in[5];
    const float* W2     = (const float*)d_in[6];
    const float* b2     = (const float*)d_in[7];
    float* out = (float*)d_out;
    const int n = in_sizes[0] / 3;           // 1048576
    const int blocks = n / NPTS_BLK;         // 8192
    gn_fused<<<dim3(blocks), dim3(256), 0, stream>>>(x, tables, W0, b0, W1, b1, W2, b2, out);
}

// Round 2
// 1086.929 us; speedup vs baseline: 1.0544x; 1.0544x over previous
//
#include <hip/hip_runtime.h>
#include <stdint.h>

#define HMAP   (1u << 19)
#define HMASK  (HMAP - 1u)
#define NPTS_BLK 128

typedef short bf16x8 __attribute__((ext_vector_type(8)));
typedef float f32x4  __attribute__((ext_vector_type(4)));

// resolutions: ceil(16 * 2^(7l/15)); dense (R^3 <= 2^19) for levels 0..4
__device__ __constant__ const int c_res[16] = {16, 23, 31, 43, 59, 81, 112, 154, 213, 295, 407, 562, 777, 1073, 1483, 2048};

__device__ __forceinline__ unsigned short f2bf(float f) {
    unsigned u = __float_as_uint(f);
    u += 0x7fffu + ((u >> 16) & 1u);           // round-to-nearest-even
    return (unsigned short)(u >> 16);
}

__device__ __forceinline__ float softplus100(float v) {
    return (v > 0.2f) ? v : 0.01f * log1pf(__expf(100.0f * v));
}

__device__ __forceinline__ float2 gather_level(const float* __restrict__ tab, int R,
                                               float x0, float x1, float x2) {
    const float Rm1 = (float)(R - 1);
    float px = x0 * Rm1, py = x1 * Rm1, pz = x2 * Rm1;
    float fx = floorf(px), fy = floorf(py), fz = floorf(pz);
    float wx = px - fx, wy = py - fy, wz = pz - fz;
    int ix = (int)fx, iy = (int)fy, iz = (int)fz;
    ix = max(0, min(ix, R - 1)); iy = max(0, min(iy, R - 1)); iz = max(0, min(iz, R - 1));
    int jx = min(ix + 1, R - 1), jy = min(iy + 1, R - 1), jz = min(iz + 1, R - 1);
    unsigned i0, i1, i2, i3, i4, i5, i6, i7;
    if ((long long)R * R * R <= (long long)HMAP) {   // dense (uniform branch per level)
        unsigned sy = (unsigned)R, sz = (unsigned)(R * R);
        unsigned X0 = (unsigned)ix, X1 = (unsigned)jx;
        unsigned Y0 = (unsigned)iy * sy, Y1 = (unsigned)jy * sy;
        unsigned Z0 = (unsigned)iz * sz, Z1 = (unsigned)jz * sz;
        i0 = X0 + Y0 + Z0; i1 = X0 + Y0 + Z1; i2 = X0 + Y1 + Z0; i3 = X0 + Y1 + Z1;
        i4 = X1 + Y0 + Z0; i5 = X1 + Y0 + Z1; i6 = X1 + Y1 + Z0; i7 = X1 + Y1 + Z1;
    } else {                                          // hashed
        unsigned X0 = (unsigned)ix, X1 = (unsigned)jx;
        unsigned Y0 = (unsigned)iy * 2654435761u, Y1 = (unsigned)jy * 2654435761u;
        unsigned Z0 = (unsigned)iz * 805459861u,  Z1 = (unsigned)jz * 805459861u;
        i0 = (X0 ^ Y0 ^ Z0) & HMASK; i1 = (X0 ^ Y0 ^ Z1) & HMASK;
        i2 = (X0 ^ Y1 ^ Z0) & HMASK; i3 = (X0 ^ Y1 ^ Z1) & HMASK;
        i4 = (X1 ^ Y0 ^ Z0) & HMASK; i5 = (X1 ^ Y0 ^ Z1) & HMASK;
        i6 = (X1 ^ Y1 ^ Z0) & HMASK; i7 = (X1 ^ Y1 ^ Z1) & HMASK;
    }
    const float2* t2 = (const float2*)tab;
    float2 v0 = t2[i0], v1 = t2[i1], v2 = t2[i2], v3 = t2[i3];
    float2 v4 = t2[i4], v5 = t2[i5], v6 = t2[i6], v7 = t2[i7];
    float ax = 1.f - wx, ay = 1.f - wy, az = 1.f - wz;
    float w00 = ay * az, w01 = ay * wz, w10 = wy * az, w11 = wy * wz;
    float c0 = ax * w00, c1 = ax * w01, c2 = ax * w10, c3 = ax * w11;
    float c4 = wx * w00, c5 = wx * w01, c6 = wx * w10, c7 = wx * w11;
    float2 r;
    r.x = c0 * v0.x + c1 * v1.x + c2 * v2.x + c3 * v3.x + c4 * v4.x + c5 * v5.x + c6 * v6.x + c7 * v7.x;
    r.y = c0 * v0.y + c1 * v1.y + c2 * v2.y + c3 * v3.y + c4 * v4.y + c5 * v5.y + c6 * v6.y + c7 * v7.y;
    return r;
}

// ======================= Kernel 1: per-(point,level) gather =======================
// Grid ordering: blocks [0, 8C) -> level = b%8 (phase 0), blocks [8C, 16C) -> level
// = 8 + b%8 (phase 1). With round-robin block->XCD, level l lives on XCD l%8 and
// levels l / l+8 are temporally separated -> each 4MB table is L2-resident on one XCD.
__global__ __launch_bounds__(256, 4)
void gather_levels(const float* __restrict__ x, const float* __restrict__ tables,
                   unsigned* __restrict__ feat, int N, int C) {
    const int b = blockIdx.x;
    const int half = 8 * C;
    const int phase = (b >= half) ? 1 : 0;
    const int r = b - phase * half;
    const int level = phase * 8 + (r & 7);
    const size_t p = (size_t)(r >> 3) * 256 + threadIdx.x;
    // x: streamed, keep out of L2 (tables own the L2)
    const float x0 = __builtin_nontemporal_load(x + 3 * p);
    const float x1 = __builtin_nontemporal_load(x + 3 * p + 1);
    const float x2 = __builtin_nontemporal_load(x + 3 * p + 2);
    float2 f = gather_level(tables + (size_t)level * (2u * HMAP), c_res[level], x0, x1, x2);
    unsigned v = (unsigned)f2bf(f.x) | ((unsigned)f2bf(f.y) << 16);
    __builtin_nontemporal_store(v, feat + (size_t)level * N + p);   // coalesced 4B/lane
}

// ======================= Kernel 2: embed + MFMA MLP =======================
// LDS layout (unsigned short units)
#define SA_STRIDE 104                     // 96 K-cols + pad
#define SA_OFF    0                       // 128 * 104
#define SB0_OFF   (128 * 104)             // W0 bf16  [64][104]  (cols 71..95 zero)
#define SB1_OFF   (SB0_OFF + 64 * 104)    // W1 bf16  [64][72]
#define SB2_OFF   (SB1_OFF + 64 * 72)     // W2 bf16  [32][72]  (rows 17..31 zero)
#define SMEM_TOT  (SB2_OFF + 32 * 72)     // 53760 B -> 3 blocks/CU

__global__ __launch_bounds__(256, 3)
void mlp_fused(const float* __restrict__ x, const unsigned* __restrict__ feat,
               const float* __restrict__ W0, const float* __restrict__ b0,
               const float* __restrict__ W1, const float* __restrict__ b1,
               const float* __restrict__ W2, const float* __restrict__ b2,
               float* __restrict__ out, int N) {
    __shared__ unsigned short smem[SMEM_TOT];
    const int tid = threadIdx.x;
    const int blk = blockIdx.x;

    // ---- stage weights as bf16 (zero-padded) ----
    for (int i = tid; i < 64 * 104; i += 256) {
        int n = i / 104, k = i - n * 104;
        smem[SB0_OFF + i] = f2bf((k < 71) ? W0[n * 71 + k] : 0.f);
    }
    for (int i = tid; i < 64 * 72; i += 256) {
        int n = i / 72, k = i - n * 72;
        smem[SB1_OFF + i] = f2bf((k < 64) ? W1[n * 64 + k] : 0.f);
    }
    for (int i = tid; i < 32 * 72; i += 256) {
        int n = i / 72, k = i - n * 72;
        smem[SB2_OFF + i] = f2bf((n < 17 && k < 64) ? W2[n * 64 + k] : 0.f);
    }

    // ---- A-tile build: threads 0-127 embed, threads 128-255 feature loads ----
    {
        const int p  = tid & 127;
        const size_t gp = (size_t)blk * NPTS_BLK + p;
        unsigned short* row = &smem[SA_OFF + p * SA_STRIDE];
        if (tid < 128) {
            const float x0 = x[3 * gp], x1 = x[3 * gp + 1], x2 = x[3 * gp + 2];
            row[0] = f2bf(x0); row[1] = f2bf(x1); row[2] = f2bf(x2);
            float fr = 1.f;
            #pragma unroll
            for (int m = 0; m < 6; ++m) {
                float a0 = x0 * fr, a1 = x1 * fr, a2 = x2 * fr;
                row[3 + 6 * m + 0] = f2bf(__sinf(a0));
                row[3 + 6 * m + 1] = f2bf(__sinf(a1));
                row[3 + 6 * m + 2] = f2bf(__sinf(a2));
                row[3 + 6 * m + 3] = f2bf(__cosf(a0));
                row[3 + 6 * m + 4] = f2bf(__cosf(a1));
                row[3 + 6 * m + 5] = f2bf(__cosf(a2));
                fr *= 2.f;
            }
            #pragma unroll
            for (int k = 71; k < 96; ++k) row[k] = 0;   // zero K-pad
        } else {
            #pragma unroll
            for (int l = 0; l < 16; ++l) {
                unsigned v = __builtin_nontemporal_load(feat + (size_t)l * N + gp);
                row[39 + 2 * l] = (unsigned short)(v & 0xffffu);
                row[40 + 2 * l] = (unsigned short)(v >> 16);
            }
        }
    }
    __syncthreads();

    // ---- MFMA pipeline: wave w -> m-half (w&1)*64, n-half (w>>1)*32 ----
    const int wave  = tid >> 6;
    const int lane  = tid & 63;
    const int mhalf = (wave & 1) * 64;
    const int nhalf = (wave >> 1);
    const int lrow  = lane & 15;
    const int quad  = lane >> 4;

    // Layer 0: [128x96] x [96x64]
    f32x4 acc0[4][2];
    #pragma unroll
    for (int mt = 0; mt < 4; ++mt)
        #pragma unroll
        for (int nt = 0; nt < 2; ++nt) acc0[mt][nt] = (f32x4){0.f, 0.f, 0.f, 0.f};
    #pragma unroll
    for (int ks = 0; ks < 3; ++ks) {
        bf16x8 bfr[2];
        #pragma unroll
        for (int nt = 0; nt < 2; ++nt) {
            int n = nhalf * 32 + nt * 16 + lrow;
            bfr[nt] = *(const bf16x8*)&smem[SB0_OFF + n * 104 + ks * 32 + quad * 8];
        }
        #pragma unroll
        for (int mt = 0; mt < 4; ++mt) {
            int m = mhalf + mt * 16 + lrow;
            bf16x8 afr = *(const bf16x8*)&smem[SA_OFF + m * SA_STRIDE + ks * 32 + quad * 8];
            #pragma unroll
            for (int nt = 0; nt < 2; ++nt)
                acc0[mt][nt] = __builtin_amdgcn_mfma_f32_16x16x32_bf16(afr, bfr[nt], acc0[mt][nt], 0, 0, 0);
        }
    }
    __syncthreads();
    #pragma unroll
    for (int mt = 0; mt < 4; ++mt)
        #pragma unroll
        for (int nt = 0; nt < 2; ++nt) {
            int colg = nhalf * 32 + nt * 16 + lrow;
            float bias = b0[colg];
            #pragma unroll
            for (int r = 0; r < 4; ++r) {
                int rowm = mhalf + mt * 16 + quad * 4 + r;
                smem[SA_OFF + rowm * SA_STRIDE + colg] = f2bf(softplus100(acc0[mt][nt][r] + bias));
            }
        }
    __syncthreads();

    // Layer 1: [128x64] x [64x64]
    f32x4 acc1[4][2];
    #pragma unroll
    for (int mt = 0; mt < 4; ++mt)
        #pragma unroll
        for (int nt = 0; nt < 2; ++nt) acc1[mt][nt] = (f32x4){0.f, 0.f, 0.f, 0.f};
    #pragma unroll
    for (int ks = 0; ks < 2; ++ks) {
        bf16x8 bfr[2];
        #pragma unroll
        for (int nt = 0; nt < 2; ++nt) {
            int n = nhalf * 32 + nt * 16 + lrow;
            bfr[nt] = *(const bf16x8*)&smem[SB1_OFF + n * 72 + ks * 32 + quad * 8];
        }
        #pragma unroll
        for (int mt = 0; mt < 4; ++mt) {
            int m = mhalf + mt * 16 + lrow;
            bf16x8 afr = *(const bf16x8*)&smem[SA_OFF + m * SA_STRIDE + ks * 32 + quad * 8];
            #pragma unroll
            for (int nt = 0; nt < 2; ++nt)
                acc1[mt][nt] = __builtin_amdgcn_mfma_f32_16x16x32_bf16(afr, bfr[nt], acc1[mt][nt], 0, 0, 0);
        }
    }
    __syncthreads();
    #pragma unroll
    for (int mt = 0; mt < 4; ++mt)
        #pragma unroll
        for (int nt = 0; nt < 2; ++nt) {
            int colg = nhalf * 32 + nt * 16 + lrow;
            float bias = b1[colg];
            #pragma unroll
            for (int r = 0; r < 4; ++r) {
                int rowm = mhalf + mt * 16 + quad * 4 + r;
                smem[SA_OFF + rowm * SA_STRIDE + colg] = f2bf(softplus100(acc1[mt][nt][r] + bias));
            }
        }
    __syncthreads();

    // Layer 2: [128x64] x [64x32] (cols 17..31 zero)
    f32x4 acc2[4];
    #pragma unroll
    for (int mt = 0; mt < 4; ++mt) acc2[mt] = (f32x4){0.f, 0.f, 0.f, 0.f};
    #pragma unroll
    for (int ks = 0; ks < 2; ++ks) {
        int n = nhalf * 16 + lrow;
        bf16x8 bfr = *(const bf16x8*)&smem[SB2_OFF + n * 72 + ks * 32 + quad * 8];
        #pragma unroll
        for (int mt = 0; mt < 4; ++mt) {
            int m = mhalf + mt * 16 + lrow;
            bf16x8 afr = *(const bf16x8*)&smem[SA_OFF + m * SA_STRIDE + ks * 32 + quad * 8];
            acc2[mt] = __builtin_amdgcn_mfma_f32_16x16x32_bf16(afr, bfr, acc2[mt], 0, 0, 0);
        }
    }
    float* sOut = (float*)&smem[SB0_OFF];
    {
        int colg = nhalf * 16 + lrow;
        if (colg < 17) {
            float bias = b2[colg];
            #pragma unroll
            for (int mt = 0; mt < 4; ++mt)
                #pragma unroll
                for (int r = 0; r < 4; ++r) {
                    int rowm = mhalf + mt * 16 + quad * 4 + r;
                    sOut[rowm * 17 + colg] = acc2[mt][r] + bias;
                }
        }
    }
    __syncthreads();
    const size_t obase = (size_t)blk * (NPTS_BLK * 17);
    for (int i = tid; i < NPTS_BLK * 17; i += 256)
        __builtin_nontemporal_store(sOut[i], out + obase + i);
}

// ======================= Fallback: round-1 fused kernel (used if ws too small) ====
__global__ __launch_bounds__(256, 3)
void gn_fused(const float* __restrict__ x, const float* __restrict__ tables,
              const float* __restrict__ W0, const float* __restrict__ b0,
              const float* __restrict__ W1, const float* __restrict__ b1,
              const float* __restrict__ W2, const float* __restrict__ b2,
              float* __restrict__ out) {
    __shared__ unsigned short smem[SMEM_TOT];
    const int tid = threadIdx.x;
    const int blk = blockIdx.x;
    for (int i = tid; i < 64 * 104; i += 256) {
        int n = i / 104, k = i - n * 104;
        smem[SB0_OFF + i] = f2bf((k < 71) ? W0[n * 71 + k] : 0.f);
    }
    for (int i = tid; i < 64 * 72; i += 256) {
        int n = i / 72, k = i - n * 72;
        smem[SB1_OFF + i] = f2bf((k < 64) ? W1[n * 64 + k] : 0.f);
    }
    for (int i = tid; i < 32 * 72; i += 256) {
        int n = i / 72, k = i - n * 72;
        smem[SB2_OFF + i] = f2bf((n < 17 && k < 64) ? W2[n * 64 + k] : 0.f);
    }
    {
        const int p  = tid & 127;
        const int gp = blk * NPTS_BLK + p;
        const float x0 = x[3 * gp], x1 = x[3 * gp + 1], x2 = x[3 * gp + 2];
        unsigned short* row = &smem[SA_OFF + p * SA_STRIDE];
        if (tid < 128) {
            row[0] = f2bf(x0); row[1] = f2bf(x1); row[2] = f2bf(x2);
            float fr = 1.f;
            #pragma unroll
            for (int m = 0; m < 6; ++m) {
                float a0 = x0 * fr, a1 = x1 * fr, a2 = x2 * fr;
                row[3 + 6 * m + 0] = f2bf(__sinf(a0));
                row[3 + 6 * m + 1] = f2bf(__sinf(a1));
                row[3 + 6 * m + 2] = f2bf(__sinf(a2));
                row[3 + 6 * m + 3] = f2bf(__cosf(a0));
                row[3 + 6 * m + 4] = f2bf(__cosf(a1));
                row[3 + 6 * m + 5] = f2bf(__cosf(a2));
                fr *= 2.f;
            }
            #pragma unroll
            for (int li = 0; li < 8; ++li) {
                const int l = 2 * li;
                float2 f = gather_level(tables + (size_t)l * (2u * HMAP), c_res[l], x0, x1, x2);
                row[39 + 2 * l] = f2bf(f.x);
                row[40 + 2 * l] = f2bf(f.y);
            }
            #pragma unroll
            for (int k = 71; k < 96; ++k) row[k] = 0;
        } else {
            #pragma unroll
            for (int li = 0; li < 8; ++li) {
                const int l = 2 * li + 1;
                float2 f = gather_level(tables + (size_t)l * (2u * HMAP), c_res[l], x0, x1, x2);
                row[39 + 2 * l] = f2bf(f.x);
                row[40 + 2 * l] = f2bf(f.y);
            }
        }
    }
    __syncthreads();
    const int wave  = tid >> 6;
    const int lane  = tid & 63;
    const int mhalf = (wave & 1) * 64;
    const int nhalf = (wave >> 1);
    const int lrow  = lane & 15;
    const int quad  = lane >> 4;
    f32x4 acc0[4][2];
    #pragma unroll
    for (int mt = 0; mt < 4; ++mt)
        #pragma unroll
        for (int nt = 0; nt < 2; ++nt) acc0[mt][nt] = (f32x4){0.f, 0.f, 0.f, 0.f};
    #pragma unroll
    for (int ks = 0; ks < 3; ++ks) {
        bf16x8 bfr[2];
        #pragma unroll
        for (int nt = 0; nt < 2; ++nt) {
            int n = nhalf * 32 + nt * 16 + lrow;
            bfr[nt] = *(const bf16x8*)&smem[SB0_OFF + n * 104 + ks * 32 + quad * 8];
        }
        #pragma unroll
        for (int mt = 0; mt < 4; ++mt) {
            int m = mhalf + mt * 16 + lrow;
            bf16x8 afr = *(const bf16x8*)&smem[SA_OFF + m * SA_STRIDE + ks * 32 + quad * 8];
            #pragma unroll
            for (int nt = 0; nt < 2; ++nt)
                acc0[mt][nt] = __builtin_amdgcn_mfma_f32_16x16x32_bf16(afr, bfr[nt], acc0[mt][nt], 0, 0, 0);
        }
    }
    __syncthreads();
    #pragma unroll
    for (int mt = 0; mt < 4; ++mt)
        #pragma unroll
        for (int nt = 0; nt < 2; ++nt) {
            int colg = nhalf * 32 + nt * 16 + lrow;
            float bias = b0[colg];
            #pragma unroll
            for (int r = 0; r < 4; ++r) {
                int rowm = mhalf + mt * 16 + quad * 4 + r;
                smem[SA_OFF + rowm * SA_STRIDE + colg] = f2bf(softplus100(acc0[mt][nt][r] + bias));
            }
        }
    __syncthreads();
    f32x4 acc1[4][2];
    #pragma unroll
    for (int mt = 0; mt < 4; ++mt)
        #pragma unroll
        for (int nt = 0; nt < 2; ++nt) acc1[mt][nt] = (f32x4){0.f, 0.f, 0.f, 0.f};
    #pragma unroll
    for (int ks = 0; ks < 2; ++ks) {
        bf16x8 bfr[2];
        #pragma unroll
        for (int nt = 0; nt < 2; ++nt) {
            int n = nhalf * 32 + nt * 16 + lrow;
            bfr[nt] = *(const bf16x8*)&smem[SB1_OFF + n * 72 + ks * 32 + quad * 8];
        }
        #pragma unroll
        for (int mt = 0; mt < 4; ++mt) {
            int m = mhalf + mt * 16 + lrow;
            bf16x8 afr = *(const bf16x8*)&smem[SA_OFF + m * SA_STRIDE + ks * 32 + quad * 8];
            #pragma unroll
            for (int nt = 0; nt < 2; ++nt)
                acc1[mt][nt] = __builtin_amdgcn_mfma_f32_16x16x32_bf16(afr, bfr[nt], acc1[mt][nt], 0, 0, 0);
        }
    }
    __syncthreads();
    #pragma unroll
    for (int mt = 0; mt < 4; ++mt)
        #pragma unroll
        for (int nt = 0; nt < 2; ++nt) {
            int colg = nhalf * 32 + nt * 16 + lrow;
            float bias = b1[colg];
            #pragma unroll
            for (int r = 0; r < 4; ++r) {
                int rowm = mhalf + mt * 16 + quad * 4 + r;
                smem[SA_OFF + rowm * SA_STRIDE + colg] = f2bf(softplus100(acc1[mt][nt][r] + bias));
            }
        }
    __syncthreads();
    f32x4 acc2[4];
    #pragma unroll
    for (int mt = 0; mt < 4; ++mt) acc2[mt] = (f32x4){0.f, 0.f, 0.f, 0.f};
    #pragma unroll
    for (int ks = 0; ks < 2; ++ks) {
        int n = nhalf * 16 + lrow;
        bf16x8 bfr = *(const bf16x8*)&smem[SB2_OFF + n * 72 + ks * 32 + quad * 8];
        #pragma unroll
        for (int mt = 0; mt < 4; ++mt) {
            int m = mhalf + mt * 16 + lrow;
            bf16x8 afr = *(const bf16x8*)&smem[SA_OFF + m * SA_STRIDE + ks * 32 + quad * 8];
            acc2[mt] = __builtin_amdgcn_mfma_f32_16x16x32_bf16(afr, bfr, acc2[mt], 0, 0, 0);
        }
    }
    float* sOut = (float*)&smem[SB0_OFF];
    {
        int colg = nhalf * 16 + lrow;
        if (colg < 17) {
            float bias = b2[colg];
            #pragma unroll
            for (int mt = 0; mt < 4; ++mt)
                #pragma unroll
                for (int r = 0; r < 4; ++r) {
                    int rowm = mhalf + mt * 16 + quad * 4 + r;
                    sOut[rowm * 17 + colg] = acc2[mt][r] + bias;
                }
        }
    }
    __syncthreads();
    const size_t obase = (size_t)blk * (NPTS_BLK * 17);
    for (int i = tid; i < NPTS_BLK * 17; i += 256) out[obase + i] = sOut[i];
}

extern "C" void kernel_launch(void* const* d_in, const int* in_sizes, int n_in,
                              void* d_out, int out_size, void* d_ws, size_t ws_size,
                              hipStream_t stream) {
    const float* x      = (const float*)d_in[0];
    const float* tables = (const float*)d_in[1];
    const float* W0     = (const float*)d_in[2];
    const float* b0     = (const float*)d_in[3];
    const float* W1     = (const float*)d_in[4];
    const float* b1     = (const float*)d_in[5];
    const float* W2     = (const float*)d_in[6];
    const float* b2     = (const float*)d_in[7];
    float* out = (float*)d_out;
    const int n = in_sizes[0] / 3;                       // 1048576
    const size_t ws_needed = (size_t)16 * n * 4;         // 16 levels x ushort2 = 64 MB
    if (ws_size >= ws_needed) {
        unsigned* feat = (unsigned*)d_ws;
        const int C = n / 256;                           // 4096 chunks per level
        gather_levels<<<dim3(16 * C), dim3(256), 0, stream>>>(x, tables, feat, n, C);
        mlp_fused<<<dim3(n / NPTS_BLK), dim3(256), 0, stream>>>(x, feat, W0, b0, W1, b1, W2, b2, out, n);
    } else {
        gn_fused<<<dim3(n / NPTS_BLK), dim3(256), 0, stream>>>(x, tables, W0, b0, W1, b1, W2, b2, out);
    }
}

// Round 3
// 694.040 us; speedup vs baseline: 1.6513x; 1.5661x over previous
//
#include <hip/hip_runtime.h>
#include <stdint.h>

#define HMAP   (1u << 19)
#define HMASK  (HMAP - 1u)

typedef short bf16x8 __attribute__((ext_vector_type(8)));
typedef float f32x4  __attribute__((ext_vector_type(4)));

// resolutions: ceil(16 * 2^(7l/15)); dense (R^3 <= 2^19) for levels 0..4
__device__ __constant__ const int c_res[16] = {16, 23, 31, 43, 59, 81, 112, 154, 213, 295, 407, 562, 777, 1073, 1483, 2048};

__device__ __forceinline__ unsigned short f2bf(float f) {
    unsigned u = __float_as_uint(f);
    u += 0x7fffu + ((u >> 16) & 1u);           // round-to-nearest-even
    return (unsigned short)(u >> 16);
}

// Exactly matches where(100v>20, v, log1p(exp(100v))/100):
// softplus(t) = max(t,0) + log1p(exp(-|t|)); branchless, native exp/log only.
__device__ __forceinline__ float softplus100(float v) {
    return fmaxf(v, 0.f) + 0.01f * __logf(1.f + __expf(-100.f * fabsf(v)));
}

__device__ __forceinline__ bf16x8 cvt8(const float* __restrict__ p) {
    f32x4 a = *(const f32x4*)p;        // p is 32B-aligned by construction
    f32x4 b = *(const f32x4*)(p + 4);
    bf16x8 r;
    r[0] = f2bf(a[0]); r[1] = f2bf(a[1]); r[2] = f2bf(a[2]); r[3] = f2bf(a[3]);
    r[4] = f2bf(b[0]); r[5] = f2bf(b[1]); r[6] = f2bf(b[2]); r[7] = f2bf(b[3]);
    return r;
}

__device__ __forceinline__ float2 gather_level(const float* __restrict__ tab, int R,
                                               float x0, float x1, float x2) {
    const float Rm1 = (float)(R - 1);
    float px = x0 * Rm1, py = x1 * Rm1, pz = x2 * Rm1;
    float fx = floorf(px), fy = floorf(py), fz = floorf(pz);
    float wx = px - fx, wy = py - fy, wz = pz - fz;
    int ix = (int)fx, iy = (int)fy, iz = (int)fz;
    ix = max(0, min(ix, R - 1)); iy = max(0, min(iy, R - 1)); iz = max(0, min(iz, R - 1));
    int jx = min(ix + 1, R - 1), jy = min(iy + 1, R - 1), jz = min(iz + 1, R - 1);
    unsigned i0, i1, i2, i3, i4, i5, i6, i7;
    if ((long long)R * R * R <= (long long)HMAP) {   // dense (uniform branch per level)
        unsigned sy = (unsigned)R, sz = (unsigned)(R * R);
        unsigned X0 = (unsigned)ix, X1 = (unsigned)jx;
        unsigned Y0 = (unsigned)iy * sy, Y1 = (unsigned)jy * sy;
        unsigned Z0 = (unsigned)iz * sz, Z1 = (unsigned)jz * sz;
        i0 = X0 + Y0 + Z0; i1 = X0 + Y0 + Z1; i2 = X0 + Y1 + Z0; i3 = X0 + Y1 + Z1;
        i4 = X1 + Y0 + Z0; i5 = X1 + Y0 + Z1; i6 = X1 + Y1 + Z0; i7 = X1 + Y1 + Z1;
    } else {                                          // hashed
        unsigned X0 = (unsigned)ix, X1 = (unsigned)jx;
        unsigned Y0 = (unsigned)iy * 2654435761u, Y1 = (unsigned)jy * 2654435761u;
        unsigned Z0 = (unsigned)iz * 805459861u,  Z1 = (unsigned)jz * 805459861u;
        i0 = (X0 ^ Y0 ^ Z0) & HMASK; i1 = (X0 ^ Y0 ^ Z1) & HMASK;
        i2 = (X0 ^ Y1 ^ Z0) & HMASK; i3 = (X0 ^ Y1 ^ Z1) & HMASK;
        i4 = (X1 ^ Y0 ^ Z0) & HMASK; i5 = (X1 ^ Y0 ^ Z1) & HMASK;
        i6 = (X1 ^ Y1 ^ Z0) & HMASK; i7 = (X1 ^ Y1 ^ Z1) & HMASK;
    }
    const float2* t2 = (const float2*)tab;
    float2 v0 = t2[i0], v1 = t2[i1], v2 = t2[i2], v3 = t2[i3];
    float2 v4 = t2[i4], v5 = t2[i5], v6 = t2[i6], v7 = t2[i7];
    float ax = 1.f - wx, ay = 1.f - wy, az = 1.f - wz;
    float w00 = ay * az, w01 = ay * wz, w10 = wy * az, w11 = wy * wz;
    float c0 = ax * w00, c1 = ax * w01, c2 = ax * w10, c3 = ax * w11;
    float c4 = wx * w00, c5 = wx * w01, c6 = wx * w10, c7 = wx * w11;
    float2 r;
    r.x = c0 * v0.x + c1 * v1.x + c2 * v2.x + c3 * v3.x + c4 * v4.x + c5 * v5.x + c6 * v6.x + c7 * v7.x;
    r.y = c0 * v0.y + c1 * v1.y + c2 * v2.y + c3 * v3.y + c4 * v4.y + c5 * v5.y + c6 * v6.y + c7 * v7.y;
    return r;
}

// ======================= Kernel 1: per-(point,level) gather =======================
// level = b%8 within each phase; phase0 = levels 0-7, phase1 = 8-15. Round-robin
// block->XCD keeps each 4MB hashed table L2-resident on exactly one XCD.
__global__ __launch_bounds__(256, 4)
void gather_levels(const float* __restrict__ x, const float* __restrict__ tables,
                   unsigned* __restrict__ feat, int N, int C) {
    const int b = blockIdx.x;
    const int half = 8 * C;
    const int phase = (b >= half) ? 1 : 0;
    const int r = b - phase * half;
    const int level = phase * 8 + (r & 7);
    const size_t p = (size_t)(r >> 3) * 256 + threadIdx.x;
    const float x0 = __builtin_nontemporal_load(x + 3 * p);
    const float x1 = __builtin_nontemporal_load(x + 3 * p + 1);
    const float x2 = __builtin_nontemporal_load(x + 3 * p + 2);
    float2 f = gather_level(tables + (size_t)level * (2u * HMAP), c_res[level], x0, x1, x2);
    unsigned v = (unsigned)f2bf(f.x) | ((unsigned)f2bf(f.y) << 16);
    __builtin_nontemporal_store(v, feat + (size_t)level * N + p);   // coalesced 4B/lane
}

// ======================= Kernel 2: tiled embed + MFMA MLP =======================
#define NPB       128                     // points per tile
#define TILES     8
#define PTS_BLK   (NPB * TILES)           // 1024 points per block
#define SA_STRIDE 104                     // shorts; 208B row stride (2-way banks, free)
#define SW0_OFF   (128 * 104)             // W0 bf16 [64][104], cols 71..95 zero
#define SMEM_SHORTS (SW0_OFF + 64 * 104)  // 19968 shorts = 39936 B -> 4 blocks/CU

__global__ __launch_bounds__(256, 4)
void mlp_tiled(const float* __restrict__ x, const unsigned* __restrict__ feat,
               const float* __restrict__ W0, const float* __restrict__ b0,
               const float* __restrict__ W1, const float* __restrict__ b1,
               const float* __restrict__ W2, const float* __restrict__ b2,
               float* __restrict__ out, int N) {
    __shared__ unsigned short smem[SMEM_SHORTS];
    const int tid  = threadIdx.x;
    const int blk  = blockIdx.x;
    const int wave = tid >> 6, lane = tid & 63;
    const int mhalf = (wave & 1) * 64;
    const int nhalf = (wave >> 1);
    const int lrow = lane & 15, quad = lane >> 4;

    // ---- once per block: stage W0 -> LDS (bf16, zero-padded cols) ----
    for (int i = tid; i < 64 * 104; i += 256) {
        int n = i / 104, k = i - n * 104;
        smem[SW0_OFF + i] = (k < 71) ? f2bf(W0[n * 71 + k]) : (unsigned short)0;
    }
    // zero A-tile pad cols 71..95 once (never rewritten: builds touch 0..70, epilogues 0..63)
    for (int i = tid; i < 128 * 25; i += 256) {
        int p = i / 25, k = i - p * 25;
        smem[p * SA_STRIDE + 71 + k] = 0;
    }
    // ---- once per block: W1/W2 fragments + biases into registers ----
    bf16x8 w1f[2][2];                       // [ks][nt]
    #pragma unroll
    for (int ks = 0; ks < 2; ++ks)
        #pragma unroll
        for (int nt = 0; nt < 2; ++nt) {
            int n = nhalf * 32 + nt * 16 + lrow;
            w1f[ks][nt] = cvt8(W1 + n * 64 + ks * 32 + quad * 8);
        }
    bf16x8 w2f[2];
    {
        int n2 = nhalf * 16 + lrow;
        #pragma unroll
        for (int ks = 0; ks < 2; ++ks) {
            if (n2 < 17) w2f[ks] = cvt8(W2 + n2 * 64 + ks * 32 + quad * 8);
            else { bf16x8 z = {0,0,0,0,0,0,0,0}; w2f[ks] = z; }
        }
    }
    float b0v[2], b1v[2], b2v;
    #pragma unroll
    for (int nt = 0; nt < 2; ++nt) {
        b0v[nt] = b0[nhalf * 32 + nt * 16 + lrow];
        b1v[nt] = b1[nhalf * 32 + nt * 16 + lrow];
    }
    { int c2 = nhalf * 16 + lrow; b2v = (c2 < 17) ? b2[c2] : 0.f; }
    __syncthreads();

    const size_t pbase0 = (size_t)blk * PTS_BLK;
    #pragma unroll 1
    for (int t = 0; t < TILES; ++t) {
        const size_t pb = pbase0 + (size_t)t * NPB;
        // ---- build A tile: sins on threads 0-127, cos+features on 128-255 ----
        {
            const int p = tid & 127;
            const size_t gp = pb + p;
            unsigned short* row = &smem[p * SA_STRIDE];
            const float x0 = __builtin_nontemporal_load(x + 3 * gp);
            const float x1 = __builtin_nontemporal_load(x + 3 * gp + 1);
            const float x2 = __builtin_nontemporal_load(x + 3 * gp + 2);
            if (tid < 128) {
                row[0] = f2bf(x0); row[1] = f2bf(x1); row[2] = f2bf(x2);
                float fr = 1.f;
                #pragma unroll
                for (int m = 0; m < 6; ++m) {
                    row[3 + 6 * m + 0] = f2bf(__sinf(x0 * fr));
                    row[3 + 6 * m + 1] = f2bf(__sinf(x1 * fr));
                    row[3 + 6 * m + 2] = f2bf(__sinf(x2 * fr));
                    fr *= 2.f;
                }
            } else {
                float fr = 1.f;
                #pragma unroll
                for (int m = 0; m < 6; ++m) {
                    row[3 + 6 * m + 3] = f2bf(__cosf(x0 * fr));
                    row[3 + 6 * m + 4] = f2bf(__cosf(x1 * fr));
                    row[3 + 6 * m + 5] = f2bf(__cosf(x2 * fr));
                    fr *= 2.f;
                }
                #pragma unroll
                for (int l = 0; l < 16; ++l) {
                    unsigned v = __builtin_nontemporal_load(feat + (size_t)l * N + gp);
                    row[39 + 2 * l] = (unsigned short)(v & 0xffffu);
                    row[40 + 2 * l] = (unsigned short)(v >> 16);
                }
            }
        }
        __syncthreads();

        // ---- Layer 0: [128x96] x [96x64] ----
        f32x4 acc0[4][2];
        #pragma unroll
        for (int mt = 0; mt < 4; ++mt)
            #pragma unroll
            for (int nt = 0; nt < 2; ++nt) acc0[mt][nt] = (f32x4){0.f, 0.f, 0.f, 0.f};
        #pragma unroll
        for (int ks = 0; ks < 3; ++ks) {
            bf16x8 bfr[2];
            #pragma unroll
            for (int nt = 0; nt < 2; ++nt) {
                int n = nhalf * 32 + nt * 16 + lrow;
                bfr[nt] = *(const bf16x8*)&smem[SW0_OFF + n * 104 + ks * 32 + quad * 8];
            }
            #pragma unroll
            for (int mt = 0; mt < 4; ++mt) {
                int m = mhalf + mt * 16 + lrow;
                bf16x8 afr = *(const bf16x8*)&smem[m * SA_STRIDE + ks * 32 + quad * 8];
                #pragma unroll
                for (int nt = 0; nt < 2; ++nt)
                    acc0[mt][nt] = __builtin_amdgcn_mfma_f32_16x16x32_bf16(afr, bfr[nt], acc0[mt][nt], 0, 0, 0);
            }
        }
        __syncthreads();   // A reads done before h0 overwrite
        #pragma unroll
        for (int mt = 0; mt < 4; ++mt)
            #pragma unroll
            for (int nt = 0; nt < 2; ++nt) {
                int colg = nhalf * 32 + nt * 16 + lrow;
                #pragma unroll
                for (int r = 0; r < 4; ++r) {
                    int rowm = mhalf + mt * 16 + quad * 4 + r;
                    smem[rowm * SA_STRIDE + colg] = f2bf(softplus100(acc0[mt][nt][r] + b0v[nt]));
                }
            }
        __syncthreads();

        // ---- Layer 1: [128x64] x [64x64], B from registers ----
        f32x4 acc1[4][2];
        #pragma unroll
        for (int mt = 0; mt < 4; ++mt)
            #pragma unroll
            for (int nt = 0; nt < 2; ++nt) acc1[mt][nt] = (f32x4){0.f, 0.f, 0.f, 0.f};
        #pragma unroll
        for (int ks = 0; ks < 2; ++ks) {
            #pragma unroll
            for (int mt = 0; mt < 4; ++mt) {
                int m = mhalf + mt * 16 + lrow;
                bf16x8 afr = *(const bf16x8*)&smem[m * SA_STRIDE + ks * 32 + quad * 8];
                #pragma unroll
                for (int nt = 0; nt < 2; ++nt)
                    acc1[mt][nt] = __builtin_amdgcn_mfma_f32_16x16x32_bf16(afr, w1f[ks][nt], acc1[mt][nt], 0, 0, 0);
            }
        }
        __syncthreads();
        #pragma unroll
        for (int mt = 0; mt < 4; ++mt)
            #pragma unroll
            for (int nt = 0; nt < 2; ++nt) {
                int colg = nhalf * 32 + nt * 16 + lrow;
                #pragma unroll
                for (int r = 0; r < 4; ++r) {
                    int rowm = mhalf + mt * 16 + quad * 4 + r;
                    smem[rowm * SA_STRIDE + colg] = f2bf(softplus100(acc1[mt][nt][r] + b1v[nt]));
                }
            }
        __syncthreads();

        // ---- Layer 2: [128x64] x [64x32], B from registers, direct store ----
        f32x4 acc2[4];
        #pragma unroll
        for (int mt = 0; mt < 4; ++mt) acc2[mt] = (f32x4){0.f, 0.f, 0.f, 0.f};
        #pragma unroll
        for (int ks = 0; ks < 2; ++ks) {
            #pragma unroll
            for (int mt = 0; mt < 4; ++mt) {
                int m = mhalf + mt * 16 + lrow;
                bf16x8 afr = *(const bf16x8*)&smem[m * SA_STRIDE + ks * 32 + quad * 8];
                acc2[mt] = __builtin_amdgcn_mfma_f32_16x16x32_bf16(afr, w2f[ks], acc2[mt], 0, 0, 0);
            }
        }
        {
            int colg = nhalf * 16 + lrow;
            if (colg < 17) {
                #pragma unroll
                for (int mt = 0; mt < 4; ++mt)
                    #pragma unroll
                    for (int r = 0; r < 4; ++r) {
                        int rowm = mhalf + mt * 16 + quad * 4 + r;
                        __builtin_nontemporal_store(acc2[mt][r] + b2v,
                                                    out + (pb + rowm) * 17 + colg);
                    }
            }
        }
        __syncthreads();   // A-tile reads complete before next build
    }
}

// ======================= Fallback (ws too small): fully fused =======================
__global__ __launch_bounds__(256, 3)
void gn_fused(const float* __restrict__ x, const float* __restrict__ tables,
              const float* __restrict__ W0, const float* __restrict__ b0,
              const float* __restrict__ W1, const float* __restrict__ b1,
              const float* __restrict__ W2, const float* __restrict__ b2,
              float* __restrict__ out) {
    __shared__ unsigned short smem[SMEM_SHORTS];
    const int tid = threadIdx.x;
    const int blk = blockIdx.x;
    const int wave = tid >> 6, lane = tid & 63;
    const int mhalf = (wave & 1) * 64;
    const int nhalf = (wave >> 1);
    const int lrow = lane & 15, quad = lane >> 4;
    for (int i = tid; i < 64 * 104; i += 256) {
        int n = i / 104, k = i - n * 104;
        smem[SW0_OFF + i] = (k < 71) ? f2bf(W0[n * 71 + k]) : (unsigned short)0;
    }
    for (int i = tid; i < 128 * 25; i += 256) {
        int p = i / 25, k = i - p * 25;
        smem[p * SA_STRIDE + 71 + k] = 0;
    }
    bf16x8 w1f[2][2];
    #pragma unroll
    for (int ks = 0; ks < 2; ++ks)
        #pragma unroll
        for (int nt = 0; nt < 2; ++nt) {
            int n = nhalf * 32 + nt * 16 + lrow;
            w1f[ks][nt] = cvt8(W1 + n * 64 + ks * 32 + quad * 8);
        }
    bf16x8 w2f[2];
    {
        int n2 = nhalf * 16 + lrow;
        #pragma unroll
        for (int ks = 0; ks < 2; ++ks) {
            if (n2 < 17) w2f[ks] = cvt8(W2 + n2 * 64 + ks * 32 + quad * 8);
            else { bf16x8 z = {0,0,0,0,0,0,0,0}; w2f[ks] = z; }
        }
    }
    float b0v[2], b1v[2], b2v;
    #pragma unroll
    for (int nt = 0; nt < 2; ++nt) {
        b0v[nt] = b0[nhalf * 32 + nt * 16 + lrow];
        b1v[nt] = b1[nhalf * 32 + nt * 16 + lrow];
    }
    { int c2 = nhalf * 16 + lrow; b2v = (c2 < 17) ? b2[c2] : 0.f; }
    {
        const int p = tid & 127;
        const size_t gp = (size_t)blk * NPB + p;
        const float x0 = x[3 * gp], x1 = x[3 * gp + 1], x2 = x[3 * gp + 2];
        unsigned short* row = &smem[p * SA_STRIDE];
        if (tid < 128) {
            row[0] = f2bf(x0); row[1] = f2bf(x1); row[2] = f2bf(x2);
            float fr = 1.f;
            #pragma unroll
            for (int m = 0; m < 6; ++m) {
                row[3 + 6 * m + 0] = f2bf(__sinf(x0 * fr));
                row[3 + 6 * m + 1] = f2bf(__sinf(x1 * fr));
                row[3 + 6 * m + 2] = f2bf(__sinf(x2 * fr));
                fr *= 2.f;
            }
            #pragma unroll
            for (int li = 0; li < 8; ++li) {
                const int l = 2 * li;
                float2 f = gather_level(tables + (size_t)l * (2u * HMAP), c_res[l], x0, x1, x2);
                row[39 + 2 * l] = f2bf(f.x);
                row[40 + 2 * l] = f2bf(f.y);
            }
        } else {
            float fr = 1.f;
            #pragma unroll
            for (int m = 0; m < 6; ++m) {
                row[3 + 6 * m + 3] = f2bf(__cosf(x0 * fr));
                row[3 + 6 * m + 4] = f2bf(__cosf(x1 * fr));
                row[3 + 6 * m + 5] = f2bf(__cosf(x2 * fr));
                fr *= 2.f;
            }
            #pragma unroll
            for (int li = 0; li < 8; ++li) {
                const int l = 2 * li + 1;
                float2 f = gather_level(tables + (size_t)l * (2u * HMAP), c_res[l], x0, x1, x2);
                row[39 + 2 * l] = f2bf(f.x);
                row[40 + 2 * l] = f2bf(f.y);
            }
        }
    }
    __syncthreads();
    f32x4 acc0[4][2];
    #pragma unroll
    for (int mt = 0; mt < 4; ++mt)
        #pragma unroll
        for (int nt = 0; nt < 2; ++nt) acc0[mt][nt] = (f32x4){0.f, 0.f, 0.f, 0.f};
    #pragma unroll
    for (int ks = 0; ks < 3; ++ks) {
        bf16x8 bfr[2];
        #pragma unroll
        for (int nt = 0; nt < 2; ++nt) {
            int n = nhalf * 32 + nt * 16 + lrow;
            bfr[nt] = *(const bf16x8*)&smem[SW0_OFF + n * 104 + ks * 32 + quad * 8];
        }
        #pragma unroll
        for (int mt = 0; mt < 4; ++mt) {
            int m = mhalf + mt * 16 + lrow;
            bf16x8 afr = *(const bf16x8*)&smem[m * SA_STRIDE + ks * 32 + quad * 8];
            #pragma unroll
            for (int nt = 0; nt < 2; ++nt)
                acc0[mt][nt] = __builtin_amdgcn_mfma_f32_16x16x32_bf16(afr, bfr[nt], acc0[mt][nt], 0, 0, 0);
        }
    }
    __syncthreads();
    #pragma unroll
    for (int mt = 0; mt < 4; ++mt)
        #pragma unroll
        for (int nt = 0; nt < 2; ++nt) {
            int colg = nhalf * 32 + nt * 16 + lrow;
            #pragma unroll
            for (int r = 0; r < 4; ++r) {
                int rowm = mhalf + mt * 16 + quad * 4 + r;
                smem[rowm * SA_STRIDE + colg] = f2bf(softplus100(acc0[mt][nt][r] + b0v[nt]));
            }
        }
    __syncthreads();
    f32x4 acc1[4][2];
    #pragma unroll
    for (int mt = 0; mt < 4; ++mt)
        #pragma unroll
        for (int nt = 0; nt < 2; ++nt) acc1[mt][nt] = (f32x4){0.f, 0.f, 0.f, 0.f};
    #pragma unroll
    for (int ks = 0; ks < 2; ++ks) {
        #pragma unroll
        for (int mt = 0; mt < 4; ++mt) {
            int m = mhalf + mt * 16 + lrow;
            bf16x8 afr = *(const bf16x8*)&smem[m * SA_STRIDE + ks * 32 + quad * 8];
            #pragma unroll
            for (int nt = 0; nt < 2; ++nt)
                acc1[mt][nt] = __builtin_amdgcn_mfma_f32_16x16x32_bf16(afr, w1f[ks][nt], acc1[mt][nt], 0, 0, 0);
        }
    }
    __syncthreads();
    #pragma unroll
    for (int mt = 0; mt < 4; ++mt)
        #pragma unroll
        for (int nt = 0; nt < 2; ++nt) {
            int colg = nhalf * 32 + nt * 16 + lrow;
            #pragma unroll
            for (int r = 0; r < 4; ++r) {
                int rowm = mhalf + mt * 16 + quad * 4 + r;
                smem[rowm * SA_STRIDE + colg] = f2bf(softplus100(acc1[mt][nt][r] + b1v[nt]));
            }
        }
    __syncthreads();
    f32x4 acc2[4];
    #pragma unroll
    for (int mt = 0; mt < 4; ++mt) acc2[mt] = (f32x4){0.f, 0.f, 0.f, 0.f};
    #pragma unroll
    for (int ks = 0; ks < 2; ++ks) {
        #pragma unroll
        for (int mt = 0; mt < 4; ++mt) {
            int m = mhalf + mt * 16 + lrow;
            bf16x8 afr = *(const bf16x8*)&smem[m * SA_STRIDE + ks * 32 + quad * 8];
            acc2[mt] = __builtin_amdgcn_mfma_f32_16x16x32_bf16(afr, w2f[ks], acc2[mt], 0, 0, 0);
        }
    }
    {
        int colg = nhalf * 16 + lrow;
        if (colg < 17) {
            #pragma unroll
            for (int mt = 0; mt < 4; ++mt)
                #pragma unroll
                for (int r = 0; r < 4; ++r) {
                    int rowm = mhalf + mt * 16 + quad * 4 + r;
                    out[((size_t)blk * NPB + rowm) * 17 + colg] = acc2[mt][r] + b2v;
                }
        }
    }
}

extern "C" void kernel_launch(void* const* d_in, const int* in_sizes, int n_in,
                              void* d_out, int out_size, void* d_ws, size_t ws_size,
                              hipStream_t stream) {
    const float* x      = (const float*)d_in[0];
    const float* tables = (const float*)d_in[1];
    const float* W0     = (const float*)d_in[2];
    const float* b0     = (const float*)d_in[3];
    const float* W1     = (const float*)d_in[4];
    const float* b1     = (const float*)d_in[5];
    const float* W2     = (const float*)d_in[6];
    const float* b2     = (const float*)d_in[7];
    float* out = (float*)d_out;
    const int n = in_sizes[0] / 3;                       // 1048576
    const size_t ws_needed = (size_t)16 * n * 4;         // 64 MB feature staging
    if (ws_size >= ws_needed) {
        unsigned* feat = (unsigned*)d_ws;
        const int C = n / 256;
        gather_levels<<<dim3(16 * C), dim3(256), 0, stream>>>(x, tables, feat, n, C);
        mlp_tiled<<<dim3(n / PTS_BLK), dim3(256), 0, stream>>>(x, feat, W0, b0, W1, b1, W2, b2, out, n);
    } else {
        gn_fused<<<dim3(n / NPB), dim3(256), 0, stream>>>(x, tables, W0, b0, W1, b1, W2, b2, out);
    }
}

// Round 4
// 596.629 us; speedup vs baseline: 1.9209x; 1.1633x over previous
//
#include <hip/hip_runtime.h>
#include <stdint.h>

#define HMAP   (1u << 19)
#define HMASK  (HMAP - 1u)

typedef short bf16x8 __attribute__((ext_vector_type(8)));
typedef float f32x4  __attribute__((ext_vector_type(4)));

// resolutions: ceil(16 * 2^(7l/15)); dense (R^3 <= 2^19) for levels 0..4
__device__ __constant__ const int c_res[16] = {16, 23, 31, 43, 59, 81, 112, 154, 213, 295, 407, 562, 777, 1073, 1483, 2048};

__device__ __forceinline__ unsigned short f2bf(float f) {
    unsigned u = __float_as_uint(f);
    u += 0x7fffu + ((u >> 16) & 1u);           // round-to-nearest-even
    return (unsigned short)(u >> 16);
}

// Exactly matches where(100v>20, v, log1p(exp(100v))/100):
// softplus(t) = max(t,0) + log1p(exp(-|t|)); branchless, native exp/log only.
__device__ __forceinline__ float softplus100(float v) {
    return fmaxf(v, 0.f) + 0.01f * __logf(1.f + __expf(-100.f * fabsf(v)));
}

__device__ __forceinline__ bf16x8 cvt8(const float* __restrict__ p) {
    f32x4 a = *(const f32x4*)p;
    f32x4 b = *(const f32x4*)(p + 4);
    bf16x8 r;
    r[0] = f2bf(a[0]); r[1] = f2bf(a[1]); r[2] = f2bf(a[2]); r[3] = f2bf(a[3]);
    r[4] = f2bf(b[0]); r[5] = f2bf(b[1]); r[6] = f2bf(b[2]); r[7] = f2bf(b[3]);
    return r;
}

// Trilinear gather with x-corner pair packing:
//  - hashed: h(x+1)=h(x)^1 when x even -> the pair {h,h^1}={2k,2k+1} is one
//    aligned 16B block regardless of h parity -> 4 dwordx4 instead of 8 dwordx2.
//  - dense: idx(x+1)=idx(x)+1 -> dwordx4 when idx even (per-pair predicate).
__device__ __forceinline__ float2 gather_level(const float* __restrict__ tab, int R,
                                               float x0, float x1, float x2) {
    const float Rm1 = (float)(R - 1);
    float px = x0 * Rm1, py = x1 * Rm1, pz = x2 * Rm1;
    float fx = floorf(px), fy = floorf(py), fz = floorf(pz);
    float wx = px - fx, wy = py - fy, wz = pz - fz;
    int ix = (int)fx, iy = (int)fy, iz = (int)fz;
    ix = max(0, min(ix, R - 1)); iy = max(0, min(iy, R - 1)); iz = max(0, min(iz, R - 1));
    int jx = min(ix + 1, R - 1), jy = min(iy + 1, R - 1), jz = min(iz + 1, R - 1);
    float ax = 1.f - wx, ay = 1.f - wy, az = 1.f - wz;
    // pair order k: (iy,iz),(jy,iz),(iy,jz),(jy,jz)
    float wyz0 = ay * az, wyz1 = wy * az, wyz2 = ay * wz, wyz3 = wy * wz;
    float2 lo[4], hi[4];                     // lo = x corner, hi = x+1 corner
    const bool adj = (jx == ix + 1);         // false only at clamped top edge
    if ((long long)R * R * R <= (long long)HMAP) {   // dense (uniform per level)
        unsigned sy = (unsigned)R, sz = (unsigned)(R * R);
        unsigned base0 = (unsigned)iy * sy + (unsigned)iz * sz;
        unsigned base1 = (unsigned)jy * sy + (unsigned)iz * sz;
        unsigned base2 = (unsigned)iy * sy + (unsigned)jz * sz;
        unsigned base3 = (unsigned)jy * sy + (unsigned)jz * sz;
        unsigned bases[4] = {base0, base1, base2, base3};
        const float2* t2 = (const float2*)tab;
        #pragma unroll
        for (int k = 0; k < 4; ++k) {
            unsigned i0 = bases[k] + (unsigned)ix;
            if (adj && !(i0 & 1u)) {
                f32x4 q = *(const f32x4*)(tab + ((size_t)i0 << 1));
                lo[k] = make_float2(q[0], q[1]);
                hi[k] = make_float2(q[2], q[3]);
            } else {
                lo[k] = t2[i0];
                hi[k] = t2[bases[k] + (unsigned)jx];
            }
        }
    } else {                                          // hashed
        unsigned hy0 = (unsigned)iy * 2654435761u, hy1 = (unsigned)jy * 2654435761u;
        unsigned hz0 = (unsigned)iz * 805459861u,  hz1 = (unsigned)jz * 805459861u;
        unsigned m0 = hy0 ^ hz0, m1 = hy1 ^ hz0, m2 = hy0 ^ hz1, m3 = hy1 ^ hz1;
        unsigned ms[4] = {m0, m1, m2, m3};
        if (adj && ((ix & 1) == 0)) {
            #pragma unroll
            for (int k = 0; k < 4; ++k) {
                unsigned h = ((unsigned)ix ^ ms[k]) & HMASK;
                f32x4 q = *(const f32x4*)(tab + ((size_t)(h & ~1u) << 1));
                float2 e0 = make_float2(q[0], q[1]);
                float2 e1 = make_float2(q[2], q[3]);
                bool sw = (h & 1u) != 0;
                lo[k] = sw ? e1 : e0;
                hi[k] = sw ? e0 : e1;
            }
        } else {
            const float2* t2 = (const float2*)tab;
            #pragma unroll
            for (int k = 0; k < 4; ++k) {
                unsigned hl = ((unsigned)ix ^ ms[k]) & HMASK;
                unsigned hh = ((unsigned)jx ^ ms[k]) & HMASK;
                lo[k] = t2[hl];
                hi[k] = t2[hh];
            }
        }
    }
    float2 r = make_float2(0.f, 0.f);
    float wyz[4] = {wyz0, wyz1, wyz2, wyz3};
    #pragma unroll
    for (int k = 0; k < 4; ++k) {
        float wl = ax * wyz[k], wh = wx * wyz[k];
        r.x += wl * lo[k].x + wh * hi[k].x;
        r.y += wl * lo[k].y + wh * hi[k].y;
    }
    return r;
}

// ======================= Kernel 1: per-(point,level) gather =======================
// phase0: level = b%8 (levels 0-7); phase1: level = 15-(b%8) -> XCD k serves levels
// {k, 15-k} (balanced cheap+expensive), each 4MB table L2-resident on one XCD.
__global__ __launch_bounds__(256, 8)
void gather_levels(const float* __restrict__ x, const float* __restrict__ tables,
                   unsigned* __restrict__ feat, int N, int C) {
    const int b = blockIdx.x;
    const int half = 8 * C;
    int r, level;
    if (b < half) { r = b; level = r & 7; }
    else          { r = b - half; level = 15 - (r & 7); }
    const size_t p = (size_t)(r >> 3) * 256 + threadIdx.x;
    const float x0 = __builtin_nontemporal_load(x + 3 * p);
    const float x1 = __builtin_nontemporal_load(x + 3 * p + 1);
    const float x2 = __builtin_nontemporal_load(x + 3 * p + 2);
    float2 f = gather_level(tables + (size_t)level * (2u * HMAP), c_res[level], x0, x1, x2);
    unsigned v = (unsigned)f2bf(f.x) | ((unsigned)f2bf(f.y) << 16);
    __builtin_nontemporal_store(v, feat + (size_t)level * N + p);   // coalesced 4B/lane
}

// ======================= Kernel 2: tiled embed + MFMA MLP =======================
#define NPB       128                     // points per tile
#define TILES     8
#define PTS_BLK   (NPB * TILES)           // 1024 points per block
#define SA_STRIDE 104                     // shorts; 208B row stride (2-way banks, free)
#define SW0_OFF   (128 * 104)             // W0 bf16 [64][104], cols 71..95 zero
#define SMEM_SHORTS (SW0_OFF + 64 * 104)  // 39936 B -> 4 blocks/CU

__global__ __launch_bounds__(256, 4)
void mlp_tiled(const float* __restrict__ x, const unsigned* __restrict__ feat,
               const float* __restrict__ W0, const float* __restrict__ b0,
               const float* __restrict__ W1, const float* __restrict__ b1,
               const float* __restrict__ W2, const float* __restrict__ b2,
               float* __restrict__ out, int N) {
    __shared__ unsigned short smem[SMEM_SHORTS];
    const int tid  = threadIdx.x;
    const int blk  = blockIdx.x;
    const int wave = tid >> 6, lane = tid & 63;
    const int mhalf = (wave & 1) * 64;
    const int nhalf = (wave >> 1);
    const int lrow = lane & 15, quad = lane >> 4;

    for (int i = tid; i < 64 * 104; i += 256) {
        int n = i / 104, k = i - n * 104;
        smem[SW0_OFF + i] = (k < 71) ? f2bf(W0[n * 71 + k]) : (unsigned short)0;
    }
    for (int i = tid; i < 128 * 25; i += 256) {
        int p = i / 25, k = i - p * 25;
        smem[p * SA_STRIDE + 71 + k] = 0;
    }
    bf16x8 w1f[2][2];
    #pragma unroll
    for (int ks = 0; ks < 2; ++ks)
        #pragma unroll
        for (int nt = 0; nt < 2; ++nt) {
            int n = nhalf * 32 + nt * 16 + lrow;
            w1f[ks][nt] = cvt8(W1 + n * 64 + ks * 32 + quad * 8);
        }
    bf16x8 w2f[2];
    {
        int n2 = nhalf * 16 + lrow;
        #pragma unroll
        for (int ks = 0; ks < 2; ++ks) {
            if (n2 < 17) w2f[ks] = cvt8(W2 + n2 * 64 + ks * 32 + quad * 8);
            else { bf16x8 z = {0,0,0,0,0,0,0,0}; w2f[ks] = z; }
        }
    }
    float b0v[2], b1v[2], b2v;
    #pragma unroll
    for (int nt = 0; nt < 2; ++nt) {
        b0v[nt] = b0[nhalf * 32 + nt * 16 + lrow];
        b1v[nt] = b1[nhalf * 32 + nt * 16 + lrow];
    }
    { int c2 = nhalf * 16 + lrow; b2v = (c2 < 17) ? b2[c2] : 0.f; }
    __syncthreads();

    const size_t pbase0 = (size_t)blk * PTS_BLK;
    #pragma unroll 1
    for (int t = 0; t < TILES; ++t) {
        const size_t pb = pbase0 + (size_t)t * NPB;
        {
            const int p = tid & 127;
            const size_t gp = pb + p;
            unsigned short* row = &smem[p * SA_STRIDE];
            const float x0 = __builtin_nontemporal_load(x + 3 * gp);
            const float x1 = __builtin_nontemporal_load(x + 3 * gp + 1);
            const float x2 = __builtin_nontemporal_load(x + 3 * gp + 2);
            if (tid < 128) {
                row[0] = f2bf(x0); row[1] = f2bf(x1); row[2] = f2bf(x2);
                float fr = 1.f;
                #pragma unroll
                for (int m = 0; m < 6; ++m) {
                    row[3 + 6 * m + 0] = f2bf(__sinf(x0 * fr));
                    row[3 + 6 * m + 1] = f2bf(__sinf(x1 * fr));
                    row[3 + 6 * m + 2] = f2bf(__sinf(x2 * fr));
                    fr *= 2.f;
                }
            } else {
                float fr = 1.f;
                #pragma unroll
                for (int m = 0; m < 6; ++m) {
                    row[3 + 6 * m + 3] = f2bf(__cosf(x0 * fr));
                    row[3 + 6 * m + 4] = f2bf(__cosf(x1 * fr));
                    row[3 + 6 * m + 5] = f2bf(__cosf(x2 * fr));
                    fr *= 2.f;
                }
                #pragma unroll
                for (int l = 0; l < 16; ++l) {
                    unsigned v = __builtin_nontemporal_load(feat + (size_t)l * N + gp);
                    row[39 + 2 * l] = (unsigned short)(v & 0xffffu);
                    row[40 + 2 * l] = (unsigned short)(v >> 16);
                }
            }
        }
        __syncthreads();

        f32x4 acc0[4][2];
        #pragma unroll
        for (int mt = 0; mt < 4; ++mt)
            #pragma unroll
            for (int nt = 0; nt < 2; ++nt) acc0[mt][nt] = (f32x4){0.f, 0.f, 0.f, 0.f};
        #pragma unroll
        for (int ks = 0; ks < 3; ++ks) {
            bf16x8 bfr[2];
            #pragma unroll
            for (int nt = 0; nt < 2; ++nt) {
                int n = nhalf * 32 + nt * 16 + lrow;
                bfr[nt] = *(const bf16x8*)&smem[SW0_OFF + n * 104 + ks * 32 + quad * 8];
            }
            #pragma unroll
            for (int mt = 0; mt < 4; ++mt) {
                int m = mhalf + mt * 16 + lrow;
                bf16x8 afr = *(const bf16x8*)&smem[m * SA_STRIDE + ks * 32 + quad * 8];
                #pragma unroll
                for (int nt = 0; nt < 2; ++nt)
                    acc0[mt][nt] = __builtin_amdgcn_mfma_f32_16x16x32_bf16(afr, bfr[nt], acc0[mt][nt], 0, 0, 0);
            }
        }
        __syncthreads();
        #pragma unroll
        for (int mt = 0; mt < 4; ++mt)
            #pragma unroll
            for (int nt = 0; nt < 2; ++nt) {
                int colg = nhalf * 32 + nt * 16 + lrow;
                #pragma unroll
                for (int r = 0; r < 4; ++r) {
                    int rowm = mhalf + mt * 16 + quad * 4 + r;
                    smem[rowm * SA_STRIDE + colg] = f2bf(softplus100(acc0[mt][nt][r] + b0v[nt]));
                }
            }
        __syncthreads();

        f32x4 acc1[4][2];
        #pragma unroll
        for (int mt = 0; mt < 4; ++mt)
            #pragma unroll
            for (int nt = 0; nt < 2; ++nt) acc1[mt][nt] = (f32x4){0.f, 0.f, 0.f, 0.f};
        #pragma unroll
        for (int ks = 0; ks < 2; ++ks) {
            #pragma unroll
            for (int mt = 0; mt < 4; ++mt) {
                int m = mhalf + mt * 16 + lrow;
                bf16x8 afr = *(const bf16x8*)&smem[m * SA_STRIDE + ks * 32 + quad * 8];
                #pragma unroll
                for (int nt = 0; nt < 2; ++nt)
                    acc1[mt][nt] = __builtin_amdgcn_mfma_f32_16x16x32_bf16(afr, w1f[ks][nt], acc1[mt][nt], 0, 0, 0);
            }
        }
        __syncthreads();
        #pragma unroll
        for (int mt = 0; mt < 4; ++mt)
            #pragma unroll
            for (int nt = 0; nt < 2; ++nt) {
                int colg = nhalf * 32 + nt * 16 + lrow;
                #pragma unroll
                for (int r = 0; r < 4; ++r) {
                    int rowm = mhalf + mt * 16 + quad * 4 + r;
                    smem[rowm * SA_STRIDE + colg] = f2bf(softplus100(acc1[mt][nt][r] + b1v[nt]));
                }
            }
        __syncthreads();

        f32x4 acc2[4];
        #pragma unroll
        for (int mt = 0; mt < 4; ++mt) acc2[mt] = (f32x4){0.f, 0.f, 0.f, 0.f};
        #pragma unroll
        for (int ks = 0; ks < 2; ++ks) {
            #pragma unroll
            for (int mt = 0; mt < 4; ++mt) {
                int m = mhalf + mt * 16 + lrow;
                bf16x8 afr = *(const bf16x8*)&smem[m * SA_STRIDE + ks * 32 + quad * 8];
                acc2[mt] = __builtin_amdgcn_mfma_f32_16x16x32_bf16(afr, w2f[ks], acc2[mt], 0, 0, 0);
            }
        }
        {
            int colg = nhalf * 16 + lrow;
            if (colg < 17) {
                #pragma unroll
                for (int mt = 0; mt < 4; ++mt)
                    #pragma unroll
                    for (int r = 0; r < 4; ++r) {
                        int rowm = mhalf + mt * 16 + quad * 4 + r;
                        __builtin_nontemporal_store(acc2[mt][r] + b2v,
                                                    out + (pb + rowm) * 17 + colg);
                    }
            }
        }
        __syncthreads();
    }
}

// ======================= Fallback (ws too small): fully fused =======================
__global__ __launch_bounds__(256, 3)
void gn_fused(const float* __restrict__ x, const float* __restrict__ tables,
              const float* __restrict__ W0, const float* __restrict__ b0,
              const float* __restrict__ W1, const float* __restrict__ b1,
              const float* __restrict__ W2, const float* __restrict__ b2,
              float* __restrict__ out) {
    __shared__ unsigned short smem[SMEM_SHORTS];
    const int tid = threadIdx.x;
    const int blk = blockIdx.x;
    const int wave = tid >> 6, lane = tid & 63;
    const int mhalf = (wave & 1) * 64;
    const int nhalf = (wave >> 1);
    const int lrow = lane & 15, quad = lane >> 4;
    for (int i = tid; i < 64 * 104; i += 256) {
        int n = i / 104, k = i - n * 104;
        smem[SW0_OFF + i] = (k < 71) ? f2bf(W0[n * 71 + k]) : (unsigned short)0;
    }
    for (int i = tid; i < 128 * 25; i += 256) {
        int p = i / 25, k = i - p * 25;
        smem[p * SA_STRIDE + 71 + k] = 0;
    }
    bf16x8 w1f[2][2];
    #pragma unroll
    for (int ks = 0; ks < 2; ++ks)
        #pragma unroll
        for (int nt = 0; nt < 2; ++nt) {
            int n = nhalf * 32 + nt * 16 + lrow;
            w1f[ks][nt] = cvt8(W1 + n * 64 + ks * 32 + quad * 8);
        }
    bf16x8 w2f[2];
    {
        int n2 = nhalf * 16 + lrow;
        #pragma unroll
        for (int ks = 0; ks < 2; ++ks) {
            if (n2 < 17) w2f[ks] = cvt8(W2 + n2 * 64 + ks * 32 + quad * 8);
            else { bf16x8 z = {0,0,0,0,0,0,0,0}; w2f[ks] = z; }
        }
    }
    float b0v[2], b1v[2], b2v;
    #pragma unroll
    for (int nt = 0; nt < 2; ++nt) {
        b0v[nt] = b0[nhalf * 32 + nt * 16 + lrow];
        b1v[nt] = b1[nhalf * 32 + nt * 16 + lrow];
    }
    { int c2 = nhalf * 16 + lrow; b2v = (c2 < 17) ? b2[c2] : 0.f; }
    {
        const int p = tid & 127;
        const size_t gp = (size_t)blk * NPB + p;
        const float x0 = x[3 * gp], x1 = x[3 * gp + 1], x2 = x[3 * gp + 2];
        unsigned short* row = &smem[p * SA_STRIDE];
        if (tid < 128) {
            row[0] = f2bf(x0); row[1] = f2bf(x1); row[2] = f2bf(x2);
            float fr = 1.f;
            #pragma unroll
            for (int m = 0; m < 6; ++m) {
                row[3 + 6 * m + 0] = f2bf(__sinf(x0 * fr));
                row[3 + 6 * m + 1] = f2bf(__sinf(x1 * fr));
                row[3 + 6 * m + 2] = f2bf(__sinf(x2 * fr));
                fr *= 2.f;
            }
            #pragma unroll
            for (int li = 0; li < 8; ++li) {
                const int l = 2 * li;
                float2 f = gather_level(tables + (size_t)l * (2u * HMAP), c_res[l], x0, x1, x2);
                row[39 + 2 * l] = f2bf(f.x);
                row[40 + 2 * l] = f2bf(f.y);
            }
        } else {
            float fr = 1.f;
            #pragma unroll
            for (int m = 0; m < 6; ++m) {
                row[3 + 6 * m + 3] = f2bf(__cosf(x0 * fr));
                row[3 + 6 * m + 4] = f2bf(__cosf(x1 * fr));
                row[3 + 6 * m + 5] = f2bf(__cosf(x2 * fr));
                fr *= 2.f;
            }
            #pragma unroll
            for (int li = 0; li < 8; ++li) {
                const int l = 2 * li + 1;
                float2 f = gather_level(tables + (size_t)l * (2u * HMAP), c_res[l], x0, x1, x2);
                row[39 + 2 * l] = f2bf(f.x);
                row[40 + 2 * l] = f2bf(f.y);
            }
        }
    }
    __syncthreads();
    f32x4 acc0[4][2];
    #pragma unroll
    for (int mt = 0; mt < 4; ++mt)
        #pragma unroll
        for (int nt = 0; nt < 2; ++nt) acc0[mt][nt] = (f32x4){0.f, 0.f, 0.f, 0.f};
    #pragma unroll
    for (int ks = 0; ks < 3; ++ks) {
        bf16x8 bfr[2];
        #pragma unroll
        for (int nt = 0; nt < 2; ++nt) {
            int n = nhalf * 32 + nt * 16 + lrow;
            bfr[nt] = *(const bf16x8*)&smem[SW0_OFF + n * 104 + ks * 32 + quad * 8];
        }
        #pragma unroll
        for (int mt = 0; mt < 4; ++mt) {
            int m = mhalf + mt * 16 + lrow;
            bf16x8 afr = *(const bf16x8*)&smem[m * SA_STRIDE + ks * 32 + quad * 8];
            #pragma unroll
            for (int nt = 0; nt < 2; ++nt)
                acc0[mt][nt] = __builtin_amdgcn_mfma_f32_16x16x32_bf16(afr, bfr[nt], acc0[mt][nt], 0, 0, 0);
        }
    }
    __syncthreads();
    #pragma unroll
    for (int mt = 0; mt < 4; ++mt)
        #pragma unroll
        for (int nt = 0; nt < 2; ++nt) {
            int colg = nhalf * 32 + nt * 16 + lrow;
            #pragma unroll
            for (int r = 0; r < 4; ++r) {
                int rowm = mhalf + mt * 16 + quad * 4 + r;
                smem[rowm * SA_STRIDE + colg] = f2bf(softplus100(acc0[mt][nt][r] + b0v[nt]));
            }
        }
    __syncthreads();
    f32x4 acc1[4][2];
    #pragma unroll
    for (int mt = 0; mt < 4; ++mt)
        #pragma unroll
        for (int nt = 0; nt < 2; ++nt) acc1[mt][nt] = (f32x4){0.f, 0.f, 0.f, 0.f};
    #pragma unroll
    for (int ks = 0; ks < 2; ++ks) {
        #pragma unroll
        for (int mt = 0; mt < 4; ++mt) {
            int m = mhalf + mt * 16 + lrow;
            bf16x8 afr = *(const bf16x8*)&smem[m * SA_STRIDE + ks * 32 + quad * 8];
            #pragma unroll
            for (int nt = 0; nt < 2; ++nt)
                acc1[mt][nt] = __builtin_amdgcn_mfma_f32_16x16x32_bf16(afr, w1f[ks][nt], acc1[mt][nt], 0, 0, 0);
        }
    }
    __syncthreads();
    #pragma unroll
    for (int mt = 0; mt < 4; ++mt)
        #pragma unroll
        for (int nt = 0; nt < 2; ++nt) {
            int colg = nhalf * 32 + nt * 16 + lrow;
            #pragma unroll
            for (int r = 0; r < 4; ++r) {
                int rowm = mhalf + mt * 16 + quad * 4 + r;
                smem[rowm * SA_STRIDE + colg] = f2bf(softplus100(acc1[mt][nt][r] + b1v[nt]));
            }
        }
    __syncthreads();
    f32x4 acc2[4];
    #pragma unroll
    for (int mt = 0; mt < 4; ++mt) acc2[mt] = (f32x4){0.f, 0.f, 0.f, 0.f};
    #pragma unroll
    for (int ks = 0; ks < 2; ++ks) {
        #pragma unroll
        for (int mt = 0; mt < 4; ++mt) {
            int m = mhalf + mt * 16 + lrow;
            bf16x8 afr = *(const bf16x8*)&smem[m * SA_STRIDE + ks * 32 + quad * 8];
            acc2[mt] = __builtin_amdgcn_mfma_f32_16x16x32_bf16(afr, w2f[ks], acc2[mt], 0, 0, 0);
        }
    }
    {
        int colg = nhalf * 16 + lrow;
        if (colg < 17) {
            #pragma unroll
            for (int mt = 0; mt < 4; ++mt)
                #pragma unroll
                for (int r = 0; r < 4; ++r) {
                    int rowm = mhalf + mt * 16 + quad * 4 + r;
                    out[((size_t)blk * NPB + rowm) * 17 + colg] = acc2[mt][r] + b2v;
                }
        }
    }
}

extern "C" void kernel_launch(void* const* d_in, const int* in_sizes, int n_in,
                              void* d_out, int out_size, void* d_ws, size_t ws_size,
                              hipStream_t stream) {
    const float* x      = (const float*)d_in[0];
    const float* tables = (const float*)d_in[1];
    const float* W0     = (const float*)d_in[2];
    const float* b0     = (const float*)d_in[3];
    const float* W1     = (const float*)d_in[4];
    const float* b1     = (const float*)d_in[5];
    const float* W2     = (const float*)d_in[6];
    const float* b2     = (const float*)d_in[7];
    float* out = (float*)d_out;
    const int n = in_sizes[0] / 3;                       // 1048576
    const size_t ws_needed = (size_t)16 * n * 4;         // 64 MB feature staging
    if (ws_size >= ws_needed) {
        unsigned* feat = (unsigned*)d_ws;
        const int C = n / 256;
        gather_levels<<<dim3(16 * C), dim3(256), 0, stream>>>(x, tables, feat, n, C);
        mlp_tiled<<<dim3(n / PTS_BLK), dim3(256), 0, stream>>>(x, feat, W0, b0, W1, b1, W2, b2, out, n);
    } else {
        gn_fused<<<dim3(n / NPB), dim3(256), 0, stream>>>(x, tables, W0, b0, W1, b1, W2, b2, out);
    }
}